// Round 1
// baseline (1189.966 us; speedup 1.0000x reference)
//
#include <hip/hip_runtime.h>

// QPooling, D=64, K=2, ND=32, B=16.
// out[b, X=(p*32+q), Y=(r*32+s)] = sum of up to 4 rho gathers:
//   t1: rho[128p+2q,   128r+2s]              always
//   t2: rho[128p+2q+1, 128r+2q+1]            iff s==q
//   t3: rho[128p+64+2q, 128p+64+2s]          iff r==p
//   t4: rho[rc, rc], rc=128p+64+2q+1         iff r==p && s==q
// rho: (16, 4096, 4096) f32; out: (16, 1024, 1024) f32. Pure gather, no atomics.
//
// R0: vectorized — each thread produces 4 consecutive Y outputs.
//   term-1 cols for s0=4k are {8k, 8k+2, 8k+4, 8k+6}+128r -> two float4 loads
//   (32B contiguous, 32B-aligned), use .x/.z of each. One float4 store.
//   4x fewer waves, ~2.7x fewer VMEM instructions vs scalar version.

#define D 64
#define DD 4096          // D*D
#define ND 32
#define ND2 1024         // ND*ND
#define BATCH 16

__global__ __launch_bounds__(256) void qpool_gather4(const float* __restrict__ rho,
                                                     float* __restrict__ out) {
    int tid = blockIdx.x * blockDim.x + threadIdx.x;  // 0 .. 4M-1, 4 outputs each
    int yq = tid & 255;          // Y0 = 4*yq, Y0 in [0,1024)
    int X  = (tid >> 8) & (ND2 - 1);
    int b  = tid >> 18;

    int k  = yq & 7;             // s0 = 4k  (4 consecutive s share one r)
    int r  = yq >> 3;
    int q  = X & (ND - 1);
    int p  = X >> 5;

    const float* base = rho + (size_t)b * DD * DD;

    // term 1: row fixed, cols 128r + {8k .. 8k+6 even} -> 2x float4, 32B aligned
    int row0 = (p << 7) + (q << 1);          // 2p*64 + 2q
    int colb = (r << 7) + (k << 3);          // 128r + 8k
    const float4* pA = (const float4*)(base + (size_t)row0 * DD + colb);
    float4 A  = pA[0];
    float4 Bv = pA[1];

    float v0 = A.x, v1 = A.z, v2 = Bv.x, v3 = Bv.z;

    // term 2: s==q possible only when q in [4k, 4k+4)
    if ((q >> 2) == k) {
        float t = base[(size_t)(row0 + 1) * DD + (r << 7) + (q << 1) + 1];
        int i = q & 3;
        if      (i == 0) v0 += t;
        else if (i == 1) v1 += t;
        else if (i == 2) v2 += t;
        else             v3 += t;
    }

    // term 3: r==p (uniform per thread; 8/64 lanes per wave at most)
    if (r == p) {
        int row2  = (p << 7) + D + (q << 1);   // (2p+1)*64 + 2q
        int col2b = (p << 7) + D + (k << 3);   // (2p+1)*64 + 8k
        const float4* pC = (const float4*)(base + (size_t)row2 * DD + col2b);
        float4 C  = pC[0];
        float4 Dv = pC[1];
        v0 += C.x; v1 += C.z; v2 += Dv.x; v3 += Dv.z;

        // term 4: diagonal element, iff additionally s==q
        if ((q >> 2) == k) {
            int rc = (p << 7) + D + (q << 1) + 1;
            float t = base[(size_t)rc * DD + rc];
            int i = q & 3;
            if      (i == 0) v0 += t;
            else if (i == 1) v1 += t;
            else if (i == 2) v2 += t;
            else             v3 += t;
        }
    }

    // out flat index (b, X, Y0) = tid*4 -> float4 store, 16B aligned
    ((float4*)out)[tid] = make_float4(v0, v1, v2, v3);
}

extern "C" void kernel_launch(void* const* d_in, const int* in_sizes, int n_in,
                              void* d_out, int out_size, void* d_ws, size_t ws_size,
                              hipStream_t stream) {
    const float* rho = (const float*)d_in[0];
    float* out = (float*)d_out;
    int total_threads = BATCH * ND2 * ND2 / 4;   // 4 outputs per thread
    int block = 256;
    int grid = total_threads / block;            // 16384
    qpool_gather4<<<grid, block, 0, stream>>>(rho, out);
}